// Round 4
// baseline (617.797 us; speedup 1.0000x reference)
//
#include <hip/hip_runtime.h>
#include <hip/hip_bf16.h>

typedef __attribute__((ext_vector_type(8))) short short8;
typedef __attribute__((ext_vector_type(4))) float f32x4;
typedef unsigned int u32;

#define LSEQ 2048
#define DMODEL 2048
#define NH 32
#define NKV 8
#define HD 64
#define WWIN 1024

__device__ inline short f2bf(float x) {
    __hip_bfloat16 h = __float2bfloat16(x);
    return __builtin_bit_cast(short, h);
}

__device__ inline void gload_lds16(const void* g, void* l) {
    __builtin_amdgcn_global_load_lds((const __attribute__((address_space(1))) u32*)g,
                                     (__attribute__((address_space(3))) u32*)l, 16, 0, 0);
}

// ---------------- cast x (f32 -> bf16), vectorized ----------------
__global__ __launch_bounds__(256) void cast_bf16(const float* __restrict__ in,
                                                 short* __restrict__ out, int n) {
    int i = (blockIdx.x * 256 + threadIdx.x) * 4;
    if (i < n) {
        float4 v = *(const float4*)&in[i];
        short4 o;
        o.x = f2bf(v.x); o.y = f2bf(v.y); o.z = f2bf(v.z); o.w = f2bf(v.w);
        *(short4*)&out[i] = o;
    }
}

// ---------- transpose + cast: in [K][N] f32 -> out [N][K] bf16 ----------
__global__ __launch_bounds__(256) void transpose_cast(const float* __restrict__ in,
                                                      short* __restrict__ out,
                                                      int K, int N) {
    __shared__ float t[64][65];
    const int k0 = blockIdx.y * 64, n0 = blockIdx.x * 64;
    const int tid = threadIdx.x;
#pragma unroll
    for (int it = 0; it < 16; ++it) {
        int c = it * 256 + tid;
        int r = c >> 6, col = c & 63;
        t[r][col] = in[(size_t)(k0 + r) * N + n0 + col];
    }
    __syncthreads();
#pragma unroll
    for (int it = 0; it < 16; ++it) {
        int c = it * 256 + tid;
        int r = c >> 6, col = c & 63;
        out[(size_t)(n0 + r) * K + k0 + col] = f2bf(t[col][r]);
    }
}

// ---------- GEMM: C[M][N] = A[M][K] @ B^T[N][K], bf16 in, f32 accum ----------
// m97 structure: 128x128 tile, BK=64, linear LDS, global_load_lds width 16.
// F32OUT: write float (for d_out, whose dtype follows the f32 reference);
// else bf16 (internal tensors).
template <int F32OUT>
__global__ __launch_bounds__(256) void gemm_bt(const short* __restrict__ A,
                                               const short* __restrict__ BT,
                                               void* __restrict__ Cv,
                                               int M, int N, int K) {
    __shared__ short At[128 * 64];    // linear, NO padding (rule #21)
    __shared__ short Bt[128 * 64];
    const int tid = threadIdx.x;
    const int lane = tid & 63, w = tid >> 6;
    const int g = lane >> 4, ln = lane & 15;
    const int row0 = blockIdx.y * 128, col0 = blockIdx.x * 128;
    const int wr = (w >> 1) * 64, wc = (w & 1) * 64;

    f32x4 acc[4][4] = {};

    for (int kt = 0; kt < K; kt += 64) {
        // stage: 1024 chunks of 16B per tile; chunk c -> row c>>3, col (c&7)*8
        // LDS dest byte = c*16 = wave-uniform base + lane*16  (rule #21 OK)
#pragma unroll
        for (int it = 0; it < 4; ++it) {
            int c = it * 256 + tid;
            int r = c >> 3, col = (c & 7) * 8;
            gload_lds16(&A[(size_t)(row0 + r) * K + kt + col], &At[c * 8]);
            gload_lds16(&BT[(size_t)(col0 + r) * K + kt + col], &Bt[c * 8]);
        }
        __syncthreads();
#pragma unroll
        for (int kb = 0; kb < 2; ++kb) {
            short8 a[4], b[4];
#pragma unroll
            for (int i = 0; i < 4; ++i) {
                a[i] = *(const short8*)&At[(wr + i * 16 + ln) * 64 + kb * 32 + g * 8];
                b[i] = *(const short8*)&Bt[(wc + i * 16 + ln) * 64 + kb * 32 + g * 8];
            }
#pragma unroll
            for (int i = 0; i < 4; ++i)
#pragma unroll
                for (int j = 0; j < 4; ++j)
                    acc[i][j] = __builtin_amdgcn_mfma_f32_16x16x32_bf16(
                        a[i], b[j], acc[i][j], 0, 0, 0);
        }
        __syncthreads();
    }
#pragma unroll
    for (int i = 0; i < 4; ++i)
#pragma unroll
        for (int j = 0; j < 4; ++j)
#pragma unroll
            for (int r = 0; r < 4; ++r) {
                int row = row0 + wr + i * 16 + g * 4 + r;
                int col = col0 + wc + j * 16 + ln;
                if (F32OUT)
                    ((float*)Cv)[(size_t)row * N + col] = acc[i][j][r];
                else
                    ((short*)Cv)[(size_t)row * N + col] = f2bf(acc[i][j][r]);
            }
}

// ---------------- windowed GQA attention (flash-style) ----------------
// grid: (L/64) * H * B blocks, 256 thr. Block = (b, h, 64 q rows); wave = 16 q rows.
__global__ __launch_bounds__(256) void attn_win(const short* __restrict__ Q,
                                                const short* __restrict__ Kg,
                                                const short* __restrict__ Vg,
                                                short* __restrict__ AO) {
    const int blk = blockIdx.x;
    const int qt = blk & 31;          // L/64 = 32
    const int h = (blk >> 5) & 31;    // H = 32
    const int b = blk >> 10;
    const int kh = h >> 2;            // repeat_interleave: head h -> kv head h/4
    const int tid = threadIdx.x, lane = tid & 63, w = tid >> 6;
    const int g = lane >> 4, ln = lane & 15;

    __shared__ short Kt[64][72];      // [kpos][d]
    __shared__ short Vt[64][72];      // transposed: [d][kpos]
    __shared__ short Pl[4][16][72];   // per-wave P tile [qrow][kpos]

    const short* Qp = Q + (size_t)(b * LSEQ) * DMODEL + h * HD;
    const short* Kp = Kg + (size_t)(b * LSEQ) * (NKV * HD) + kh * HD;
    const short* Vp = Vg + (size_t)(b * LSEQ) * (NKV * HD) + kh * HD;

    const int qbase = qt * 64 + w * 16;

    short8 aq[2];
    aq[0] = *(const short8*)&Qp[(size_t)(qbase + ln) * DMODEL + g * 8];
    aq[1] = *(const short8*)&Qp[(size_t)(qbase + ln) * DMODEL + 32 + g * 8];

    f32x4 acc[4] = {};
    float m_run[4], lsum[4];
#pragma unroll
    for (int r = 0; r < 4; ++r) { m_run[r] = -1e20f; lsum[r] = 0.f; }

    for (int kt = 0; kt < LSEQ; kt += 64) {
        // stage K tile and transposed V tile
#pragma unroll
        for (int it = 0; it < 2; ++it) {
            int c = it * 256 + tid;       // 512 chunks of 8
            int r = c >> 3, col = (c & 7) * 8;
            *(int4*)&Kt[r][col] = *(const int4*)&Kp[(size_t)(kt + r) * (NKV * HD) + col];
            int4 vv = *(const int4*)&Vp[(size_t)(kt + r) * (NKV * HD) + col];
            short8 v8 = __builtin_bit_cast(short8, vv);
#pragma unroll
            for (int j = 0; j < 8; ++j) Vt[col + j][r] = v8[j];
        }
        __syncthreads();

        // S = Q K^T (16 q rows x 64 k cols per wave)
        f32x4 s[4];
#pragma unroll
        for (int nt = 0; nt < 4; ++nt) {
            s[nt] = (f32x4){0.f, 0.f, 0.f, 0.f};
#pragma unroll
            for (int db = 0; db < 2; ++db) {
                short8 bk = *(const short8*)&Kt[nt * 16 + ln][db * 32 + g * 8];
                s[nt] = __builtin_amdgcn_mfma_f32_16x16x32_bf16(aq[db], bk, s[nt], 0, 0, 0);
            }
        }

        // scale + window mask: masked iff (j >= i-W) && (j < i)
        float p[4][4];
        float tmax[4] = {-1e30f, -1e30f, -1e30f, -1e30f};
#pragma unroll
        for (int nt = 0; nt < 4; ++nt)
#pragma unroll
            for (int r = 0; r < 4; ++r) {
                int i = qbase + g * 4 + r;
                int j = kt + nt * 16 + ln;
                float sv = s[nt][r] * 0.125f;
                bool masked = (j >= i - WWIN) && (j < i);
                sv = masked ? -1e30f : sv;
                p[nt][r] = sv;
                tmax[r] = fmaxf(tmax[r], sv);
            }

        // online softmax update, row-parallel across the 16-lane group
#pragma unroll
        for (int r = 0; r < 4; ++r) {
            float t = tmax[r];
            t = fmaxf(t, __shfl_xor(t, 1));
            t = fmaxf(t, __shfl_xor(t, 2));
            t = fmaxf(t, __shfl_xor(t, 4));
            t = fmaxf(t, __shfl_xor(t, 8));
            float Mn = fmaxf(m_run[r], t);   // m_run floored at -1e20 -> safe
            float scale = __expf(m_run[r] - Mn);
            m_run[r] = Mn;
            float rs = 0.f;
#pragma unroll
            for (int nt = 0; nt < 4; ++nt) {
                float pv = __expf(p[nt][r] - Mn);  // masked: exp(~-1e30) = 0
                p[nt][r] = pv;
                rs += pv;
            }
            rs += __shfl_xor(rs, 1);
            rs += __shfl_xor(rs, 2);
            rs += __shfl_xor(rs, 4);
            rs += __shfl_xor(rs, 8);
            lsum[r] = lsum[r] * scale + rs;
#pragma unroll
            for (int dt = 0; dt < 4; ++dt) acc[dt][r] *= scale;
        }

        // P -> per-wave LDS (redistribute D-layout -> A-frag layout)
#pragma unroll
        for (int r = 0; r < 4; ++r)
#pragma unroll
            for (int nt = 0; nt < 4; ++nt)
                Pl[w][g * 4 + r][nt * 16 + ln] = f2bf(p[nt][r]);
        asm volatile("s_waitcnt lgkmcnt(0)" ::: "memory");

        // PV: acc += P @ V
#pragma unroll
        for (int kb = 0; kb < 2; ++kb) {
            short8 pa = *(const short8*)&Pl[w][ln][kb * 32 + g * 8];
#pragma unroll
            for (int dt = 0; dt < 4; ++dt) {
                short8 bv = *(const short8*)&Vt[dt * 16 + ln][kb * 32 + g * 8];
                acc[dt] = __builtin_amdgcn_mfma_f32_16x16x32_bf16(pa, bv, acc[dt], 0, 0, 0);
            }
        }
        __syncthreads();
    }

    // epilogue: AO[b, row, h, d] bf16
#pragma unroll
    for (int dt = 0; dt < 4; ++dt)
#pragma unroll
        for (int r = 0; r < 4; ++r) {
            int row = qbase + g * 4 + r;
            float v = acc[dt][r] / lsum[r];
            AO[(size_t)(b * LSEQ + row) * DMODEL + h * HD + dt * 16 + ln] = f2bf(v);
        }
}

extern "C" void kernel_launch(void* const* d_in, const int* in_sizes, int n_in,
                              void* d_out, int out_size, void* d_ws, size_t ws_size,
                              hipStream_t stream) {
    const float* x = (const float*)d_in[0];
    const float* wq = (const float*)d_in[1];
    const float* wk = (const float*)d_in[2];
    const float* wv = (const float*)d_in[3];
    const float* wo = (const float*)d_in[4];

    const int B = 2, L = LSEQ, D = DMODEL;
    const int M = B * L;          // 4096
    const int KVD = NKV * HD;     // 512

    char* ws = (char*)d_ws;
    size_t off = 0;
    auto alloc = [&](size_t bytes) { char* p = ws + off; off += (bytes + 255) & ~(size_t)255; return p; };
    short* xb  = (short*)alloc((size_t)M * D * 2);
    short* wqT = (short*)alloc((size_t)D * D * 2);
    short* wkT = (short*)alloc((size_t)KVD * D * 2);
    short* wvT = (short*)alloc((size_t)KVD * D * 2);
    short* woT = (short*)alloc((size_t)D * D * 2);
    short* Qb  = (short*)alloc((size_t)M * D * 2);
    short* Kb  = (short*)alloc((size_t)M * KVD * 2);
    short* Vb  = (short*)alloc((size_t)M * KVD * 2);
    short* AO  = (short*)alloc((size_t)M * D * 2);

    // 1. casts / transposes
    cast_bf16<<<(M * D / 4 + 255) / 256, 256, 0, stream>>>(x, xb, M * D);
    transpose_cast<<<dim3(D / 64, D / 64), 256, 0, stream>>>(wq, wqT, D, D);
    transpose_cast<<<dim3(KVD / 64, D / 64), 256, 0, stream>>>(wk, wkT, D, KVD);
    transpose_cast<<<dim3(KVD / 64, D / 64), 256, 0, stream>>>(wv, wvT, D, KVD);
    transpose_cast<<<dim3(D / 64, D / 64), 256, 0, stream>>>(wo, woT, D, D);

    // 2. projections (bf16 internal outputs)
    gemm_bt<0><<<dim3(D / 128, M / 128), 256, 0, stream>>>(xb, wqT, Qb, M, D, D);
    gemm_bt<0><<<dim3(KVD / 128, M / 128), 256, 0, stream>>>(xb, wkT, Kb, M, KVD, D);
    gemm_bt<0><<<dim3(KVD / 128, M / 128), 256, 0, stream>>>(xb, wvT, Vb, M, KVD, D);

    // 3. attention
    attn_win<<<B * NH * (L / 64), 256, 0, stream>>>(Qb, Kb, Vb, AO);

    // 4. output projection -> FLOAT out (reference output dtype is f32)
    gemm_bt<1><<<dim3(D / 128, M / 128), 256, 0, stream>>>(AO, woT, d_out, M, D, D);
}

// Round 6
// 523.456 us; speedup vs baseline: 1.1802x; 1.1802x over previous
//
#include <hip/hip_runtime.h>
#include <hip/hip_bf16.h>

typedef __attribute__((ext_vector_type(8))) short short8;
typedef __attribute__((ext_vector_type(4))) float f32x4;
typedef unsigned int u32;

#define LSEQ 2048
#define DMODEL 2048
#define NH 32
#define NKV 8
#define HD 64
#define WWIN 1024
#define KVD (NKV * HD)   // 512

__device__ inline short f2bf(float x) {
    __hip_bfloat16 h = __float2bfloat16(x);
    return __builtin_bit_cast(short, h);
}

__device__ inline void gload_lds16(const void* g, void* l) {
    __builtin_amdgcn_global_load_lds((const __attribute__((address_space(1))) u32*)g,
                                     (__attribute__((address_space(3))) u32*)l, 16, 0, 0);
}

// ---------------- cast x (f32 -> bf16), vectorized ----------------
__global__ __launch_bounds__(256) void cast_bf16(const float* __restrict__ in,
                                                 short* __restrict__ out, int n) {
    int i = (blockIdx.x * 256 + threadIdx.x) * 4;
    if (i < n) {
        float4 v = *(const float4*)&in[i];
        short4 o;
        o.x = f2bf(v.x); o.y = f2bf(v.y); o.z = f2bf(v.z); o.w = f2bf(v.w);
        *(short4*)&out[i] = o;
    }
}

// ---------- transpose + cast: in [K][N] f32 -> out [N][K] bf16 ----------
__global__ __launch_bounds__(256) void transpose_cast(const float* __restrict__ in,
                                                      short* __restrict__ out,
                                                      int K, int N) {
    __shared__ float t[64][65];
    const int k0 = blockIdx.y * 64, n0 = blockIdx.x * 64;
    const int tid = threadIdx.x;
#pragma unroll
    for (int it = 0; it < 16; ++it) {
        int c = it * 256 + tid;
        int r = c >> 6, col = c & 63;
        t[r][col] = in[(size_t)(k0 + r) * N + n0 + col];
    }
    __syncthreads();
#pragma unroll
    for (int it = 0; it < 16; ++it) {
        int c = it * 256 + tid;
        int r = c >> 6, col = c & 63;
        out[(size_t)(n0 + r) * K + k0 + col] = f2bf(t[col][r]);
    }
}

// ---------- GEMM: C[M][N] = A[M][K] @ B^T[N][K], bf16 in, f32 accum ----------
// m97 structure: 128x128 tile, BK=64, linear LDS, global_load_lds width 16.
template <int F32OUT>
__global__ __launch_bounds__(256) void gemm_bt(const short* __restrict__ A,
                                               const short* __restrict__ BT,
                                               void* __restrict__ Cv,
                                               int M, int N, int K) {
    __shared__ short At[128 * 64];    // linear, NO padding (rule #21)
    __shared__ short Bt[128 * 64];
    const int tid = threadIdx.x;
    const int lane = tid & 63, w = tid >> 6;
    const int g = lane >> 4, ln = lane & 15;
    const int row0 = blockIdx.y * 128, col0 = blockIdx.x * 128;
    const int wr = (w >> 1) * 64, wc = (w & 1) * 64;

    f32x4 acc[4][4] = {};

    for (int kt = 0; kt < K; kt += 64) {
#pragma unroll
        for (int it = 0; it < 4; ++it) {
            int c = it * 256 + tid;
            int r = c >> 3, col = (c & 7) * 8;
            gload_lds16(&A[(size_t)(row0 + r) * K + kt + col], &At[c * 8]);
            gload_lds16(&BT[(size_t)(col0 + r) * K + kt + col], &Bt[c * 8]);
        }
        __syncthreads();
#pragma unroll
        for (int kb = 0; kb < 2; ++kb) {
            short8 a[4], b[4];
#pragma unroll
            for (int i = 0; i < 4; ++i) {
                a[i] = *(const short8*)&At[(wr + i * 16 + ln) * 64 + kb * 32 + g * 8];
                b[i] = *(const short8*)&Bt[(wc + i * 16 + ln) * 64 + kb * 32 + g * 8];
            }
#pragma unroll
            for (int i = 0; i < 4; ++i)
#pragma unroll
                for (int j = 0; j < 4; ++j)
                    acc[i][j] = __builtin_amdgcn_mfma_f32_16x16x32_bf16(
                        a[i], b[j], acc[i][j], 0, 0, 0);
        }
        __syncthreads();
    }
#pragma unroll
    for (int i = 0; i < 4; ++i)
#pragma unroll
        for (int j = 0; j < 4; ++j)
#pragma unroll
            for (int r = 0; r < 4; ++r) {
                int row = row0 + wr + i * 16 + g * 4 + r;
                int col = col0 + wc + j * 16 + ln;
                if (F32OUT)
                    ((float*)Cv)[(size_t)row * N + col] = acc[i][j][r];
                else
                    ((short*)Cv)[(size_t)row * N + col] = f2bf(acc[i][j][r]);
            }
}

// ---------------- windowed GQA attention (flash-style) ----------------
// grid: (L/64)*H*B blocks, 256 thr. Block = (b, h, 64 q rows); wave = 16 q rows.
// K staged row-major [kpos][d], V^T staged [d][kpos]; both linear [64][64] LDS
// with XOR chunk-swizzle (source-side pre-swizzle, rule #21).
__global__ __launch_bounds__(256) void attn_win(const short* __restrict__ Q,
                                                const short* __restrict__ Kg,
                                                const short* __restrict__ VT,
                                                short* __restrict__ AO) {
    const int blk = blockIdx.x;
    const int qt = blk & 31;          // L/64 = 32
    const int h = (blk >> 5) & 31;    // H = 32
    const int b = blk >> 10;
    const int kh = h >> 2;            // repeat_interleave: head h -> kv head h/4
    const int tid = threadIdx.x, lane = tid & 63, w = tid >> 6;
    const int g = lane >> 4, ln = lane & 15;

    __shared__ short Kt[64 * 64];     // [kpos][d], swizzled chunks
    __shared__ short Vt[64 * 64];     // [d][kpos], swizzled chunks
    __shared__ short Pl[4][16 * 64];  // per-wave P tile, swizzled bytes

    const short* Qp = Q + (size_t)(b * LSEQ) * DMODEL + h * HD;
    const short* Kp = Kg + (size_t)(b * LSEQ) * KVD + kh * HD;
    // VT layout: [(kv*64+d)][b*L + kpos], row stride B*L = 4096
    const short* VTp = VT + (size_t)(kh * HD) * (2 * LSEQ) + b * LSEQ;

    const int qbase = qt * 64 + w * 16;

    short8 aq[2];
    aq[0] = *(const short8*)&Qp[(size_t)(qbase + ln) * DMODEL + g * 8];
    aq[1] = *(const short8*)&Qp[(size_t)(qbase + ln) * DMODEL + 32 + g * 8];

    f32x4 acc[4] = {};
    float m_run[4], lsum[4];
#pragma unroll
    for (int r = 0; r < 4; ++r) { m_run[r] = -1e20f; lsum[r] = 0.f; }

    for (int kt = 0; kt < LSEQ; kt += 64) {
        // stage K and V^T: 512 chunks of 16B each; source chunk pre-swizzled
#pragma unroll
        for (int it = 0; it < 2; ++it) {
            int c = it * 256 + tid;
            int r = c >> 3, cc = c & 7;
            int sc = cc ^ (r & 7);    // XOR source pre-swizzle (rule #21)
            gload_lds16(&Kp[(size_t)(kt + r) * KVD + sc * 8], &Kt[c * 8]);
            gload_lds16(&VTp[(size_t)r * (2 * LSEQ) + kt + sc * 8], &Vt[c * 8]);
        }
        __syncthreads();

        // S = Q K^T (16 q rows x 64 k cols per wave)
        f32x4 s[4];
#pragma unroll
        for (int nt = 0; nt < 4; ++nt) {
            s[nt] = (f32x4){0.f, 0.f, 0.f, 0.f};
#pragma unroll
            for (int kb = 0; kb < 2; ++kb) {
                int row = nt * 16 + ln;
                int csw = (kb * 4 + g) ^ (row & 7);
                short8 bk = *(const short8*)&Kt[row * 64 + csw * 8];
                s[nt] = __builtin_amdgcn_mfma_f32_16x16x32_bf16(aq[kb], bk, s[nt], 0, 0, 0);
            }
        }

        // scale + window mask: masked iff (j >= i-W) && (j < i)
        float p[4][4];
        float tmax[4] = {-1e30f, -1e30f, -1e30f, -1e30f};
#pragma unroll
        for (int nt = 0; nt < 4; ++nt)
#pragma unroll
            for (int r = 0; r < 4; ++r) {
                int i = qbase + g * 4 + r;
                int j = kt + nt * 16 + ln;
                float sv = s[nt][r] * 0.125f;
                bool masked = (j >= i - WWIN) && (j < i);
                sv = masked ? -1e30f : sv;
                p[nt][r] = sv;
                tmax[r] = fmaxf(tmax[r], sv);
            }

        // online softmax, row-parallel across the 16-lane group
#pragma unroll
        for (int r = 0; r < 4; ++r) {
            float t = tmax[r];
            t = fmaxf(t, __shfl_xor(t, 1));
            t = fmaxf(t, __shfl_xor(t, 2));
            t = fmaxf(t, __shfl_xor(t, 4));
            t = fmaxf(t, __shfl_xor(t, 8));
            float Mn = fmaxf(m_run[r], t);   // m_run floored at -1e20 -> safe
            float scale = __expf(m_run[r] - Mn);
            m_run[r] = Mn;
            float rs = 0.f;
#pragma unroll
            for (int nt = 0; nt < 4; ++nt) {
                float pv = __expf(p[nt][r] - Mn);
                p[nt][r] = pv;
                rs += pv;
            }
            rs += __shfl_xor(rs, 1);
            rs += __shfl_xor(rs, 2);
            rs += __shfl_xor(rs, 4);
            rs += __shfl_xor(rs, 8);
            lsum[r] = lsum[r] * scale + rs;
#pragma unroll
            for (int dt = 0; dt < 4; ++dt) acc[dt][r] *= scale;
        }

        // P -> per-wave LDS (swizzled bytes: elem (row,col) at row*128 + (col*2 ^ ((row&7)<<4)))
        char* plb = (char*)&Pl[w][0];
#pragma unroll
        for (int r = 0; r < 4; ++r) {
            int prow = g * 4 + r;
            int pbase = prow * 128;
            int px = (prow & 7) << 4;
#pragma unroll
            for (int nt = 0; nt < 4; ++nt) {
                int col = nt * 16 + ln;
                *(short*)(plb + pbase + ((col * 2) ^ px)) = f2bf(p[nt][r]);
            }
        }
        asm volatile("s_waitcnt lgkmcnt(0)" ::: "memory");

        // PV: acc += P @ V  (pa row = ln; bv row = dt*16+ln from V^T)
#pragma unroll
        for (int kb = 0; kb < 2; ++kb) {
            short8 pa = *(const short8*)(plb + ln * 128 + (((kb * 32 + g * 8) * 2) ^ ((ln & 7) << 4)));
#pragma unroll
            for (int dt = 0; dt < 4; ++dt) {
                int row = dt * 16 + ln;
                int csw = (kb * 4 + g) ^ (row & 7);
                short8 bv = *(const short8*)&Vt[row * 64 + csw * 8];
                acc[dt] = __builtin_amdgcn_mfma_f32_16x16x32_bf16(pa, bv, acc[dt], 0, 0, 0);
            }
        }
        __syncthreads();
    }

    // epilogue: AO[b, row, h, d] bf16
#pragma unroll
    for (int dt = 0; dt < 4; ++dt)
#pragma unroll
        for (int r = 0; r < 4; ++r) {
            int row = qbase + g * 4 + r;
            float v = acc[dt][r] / lsum[r];
            AO[(size_t)(b * LSEQ + row) * DMODEL + h * HD + dt * 16 + ln] = f2bf(v);
        }
}

extern "C" void kernel_launch(void* const* d_in, const int* in_sizes, int n_in,
                              void* d_out, int out_size, void* d_ws, size_t ws_size,
                              hipStream_t stream) {
    const float* x = (const float*)d_in[0];
    const float* wq = (const float*)d_in[1];
    const float* wk = (const float*)d_in[2];
    const float* wv = (const float*)d_in[3];
    const float* wo = (const float*)d_in[4];

    const int B = 2, L = LSEQ, D = DMODEL;
    const int M = B * L;          // 4096

    char* ws = (char*)d_ws;
    size_t off = 0;
    auto alloc = [&](size_t bytes) { char* p = ws + off; off += (bytes + 255) & ~(size_t)255; return p; };
    short* xb  = (short*)alloc((size_t)M * D * 2);
    short* wqT = (short*)alloc((size_t)D * D * 2);
    short* wkT = (short*)alloc((size_t)KVD * D * 2);
    short* wvT = (short*)alloc((size_t)KVD * D * 2);
    short* woT = (short*)alloc((size_t)D * D * 2);
    short* Qb  = (short*)alloc((size_t)M * D * 2);
    short* Kb  = (short*)alloc((size_t)M * KVD * 2);
    short* VT  = (short*)alloc((size_t)M * KVD * 2);   // [KVD][M] = [kv*64+d][b*L+kpos]
    short* AO  = (short*)alloc((size_t)M * D * 2);

    // 1. casts / transposes
    cast_bf16<<<(M * D / 4 + 255) / 256, 256, 0, stream>>>(x, xb, M * D);
    transpose_cast<<<dim3(D / 64, D / 64), 256, 0, stream>>>(wq, wqT, D, D);
    transpose_cast<<<dim3(KVD / 64, D / 64), 256, 0, stream>>>(wk, wkT, D, KVD);
    transpose_cast<<<dim3(KVD / 64, D / 64), 256, 0, stream>>>(wv, wvT, D, KVD);
    transpose_cast<<<dim3(D / 64, D / 64), 256, 0, stream>>>(wo, woT, D, D);

    // 2. projections (bf16 internal outputs)
    gemm_bt<0><<<dim3(D / 128, M / 128), 256, 0, stream>>>(xb, wqT, Qb, M, D, D);
    gemm_bt<0><<<dim3(KVD / 128, M / 128), 256, 0, stream>>>(xb, wkT, Kb, M, KVD, D);
    // V^T directly as a GEMM: VT[n][seq] = sum_k wvT[n][k] * xb[seq][k]
    gemm_bt<0><<<dim3(M / 128, KVD / 128), 256, 0, stream>>>(wvT, xb, VT, KVD, M, D);

    // 3. attention
    attn_win<<<B * NH * (L / 64), 256, 0, stream>>>(Qb, Kb, VT, AO);

    // 4. output projection -> FLOAT out (reference output dtype is f32)
    gemm_bt<1><<<dim3(D / 128, M / 128), 256, 0, stream>>>(AO, woT, d_out, M, D, D);
}